// Round 9
// baseline (561.200 us; speedup 1.0000x reference)
//
#include <hip/hip_runtime.h>
#include <math.h>

// B=8, C=64, H=512, W=512, K=8, HID=64, nh=nw=64, L=4096
//
//  A) mlp_precompute: pk[L][64], pb[L] into d_ws (runs once, ~8 us).
//  B) afpm_main (R9): no register-resident pixels. Phase 1 streams the tile
//     (read x once from HBM), computes per-patch dots; ONE barrier; per-thread
//     conv; Phase 2 re-reads the same pixels (L3-resident, ~free at HBM level)
//     and stores modulated output. VGPR ~48 -> 2 blocks/CU at 1024 threads
//     (32 waves, 100% occupancy): cross-block overlap hides each block's
//     compute/barrier/drain phases.
//     Thread (c,u): owns patch u (8x8) of plane c end-to-end: dot needs no
//     shuffle, conv modulator is consumed by the thread that computes it.
//     Tile = 64c x 8r x 128 cols -> 512 B per (c,row) per block (R8's proven
//     write-granule geometry). Grid (4, 64, 8) = 2048 blocks.

static __device__ __forceinline__ float gelu_erf(float x) {
    return 0.5f * x * (1.0f + erff(x * 0.70710678118654752f));
}

__global__ __launch_bounds__(256) void mlp_precompute(
    const float* __restrict__ w1k, const float* __restrict__ b1k,
    const float* __restrict__ w2k, const float* __restrict__ b2k,
    const float* __restrict__ w1b, const float* __restrict__ b1b,
    const float* __restrict__ w2b, const float* __restrict__ b2b,
    float* __restrict__ pk_out,   // [L][64]
    float* __restrict__ pb_out)   // [L]
{
    constexpr int HID = 64;
    const int tid = threadIdx.x;
    const int pi  = tid >> 6;
    const int j   = tid & 63;
    const int l   = blockIdx.x * 4 + pi;

    const int py_i = l >> 6;
    const int px_i = l & 63;
    const float py = (float)(py_i * 8) + 4.0f - 256.0f;
    const float px = (float)(px_i * 8) + 4.0f - 256.0f;
    const float dd = sqrtf(py * py + px * px) * (1.0f / 362.03867196751236f);

    __shared__ float gk[4][HID];
    __shared__ float gb[4][HID];

    gk[pi][j] = gelu_erf(dd * w1k[j] + b1k[j]);
    gb[pi][j] = gelu_erf(dd * w1b[j] + b1b[j]);
    __syncthreads();

    float s = b2k[j];
#pragma unroll 8
    for (int h = 0; h < HID; ++h)
        s += gk[pi][h] * w2k[h * HID + j];
    pk_out[l * HID + j] = s;

    if (j == 0) {
        float t = b2b[0];
        for (int h = 0; h < HID; ++h)
            t += gb[pi][h] * w2b[h];
        pb_out[l] = t;
    }
}

__global__ __launch_bounds__(1024, 8) void afpm_main(
    const float* __restrict__ x,
    const float* __restrict__ conv_w, const float* __restrict__ conv_b,
    const float* __restrict__ pk_g,   // [L][64]
    const float* __restrict__ pb_g,   // [L]
    float* __restrict__ out)
{
    constexpr int W = 512;

    const int tid  = threadIdx.x;
    const int u    = tid & 15;         // 0..15: patch within tile
    const int c    = tid >> 4;         // 0..63: channel
    const int tile = blockIdx.x;       // 0..3 : 128-col tile
    const int ph   = blockIdx.y;       // 0..63
    const int b    = blockIdx.z;       // 0..7

    __shared__ float f0T[16][68];      // [patch][cc], pad 68

    const int l = ph * 64 + tile * 16 + u;   // this thread's global patch

    const size_t base = (((size_t)b * 64 + c) * 512 + (size_t)ph * 8) * (size_t)W
                        + (size_t)(tile * 128);
    const float* xp = x + base + u * 8;            // this thread's patch cols
    const float* kp = pk_g + (size_t)l * 64;       // its dynamic kernel (L2-hot)

    // ---- Phase 1: streaming dot; pixels NOT kept in registers ----
    float s = 0.0f;
#pragma unroll
    for (int r = 0; r < 8; ++r) {
        const float4 xa = *(const float4*)(xp + r * W);
        const float4 xb = *(const float4*)(xp + r * W + 4);
        const float4 ka = *(const float4*)(kp + r * 8);
        const float4 kb = *(const float4*)(kp + r * 8 + 4);
        s += xa.x * ka.x + xa.y * ka.y + xa.z * ka.z + xa.w * ka.w
           + xb.x * kb.x + xb.y * kb.y + xb.z * kb.z + xb.w * kb.w;
    }
    f0T[u][c] = s + pb_g[l];
    __syncthreads();                   // the ONE barrier

    // ---- conv: thread (c,u) computes ITS OWN modulator (o=c, patch=u) ----
    float t = 0.0f;
    const float4* cw = (const float4*)(conv_w + (size_t)c * 64);
#pragma unroll
    for (int i = 0; i < 16; ++i) {
        const float4 w = cw[i];
        const float4 f = *(const float4*)&f0T[u][i * 4];
        t += w.x * f.x + w.y * f.y + w.z * f.z + w.w * f.w;
    }
    const float m = t + conv_b[c];

    // ---- Phase 2: re-read pixels (L3-resident), modulate, store ----
    float* op = out + base + u * 8;
#pragma unroll
    for (int r = 0; r < 8; ++r) {
        float4 xa = *(const float4*)(xp + r * W);
        float4 xb = *(const float4*)(xp + r * W + 4);
        xa.x *= m; xa.y *= m; xa.z *= m; xa.w *= m;
        xb.x *= m; xb.y *= m; xb.z *= m; xb.w *= m;
        *(float4*)(op + r * W)     = xa;
        *(float4*)(op + r * W + 4) = xb;
    }
}

extern "C" void kernel_launch(void* const* d_in, const int* in_sizes, int n_in,
                              void* d_out, int out_size, void* d_ws, size_t ws_size,
                              hipStream_t stream) {
    const float* x      = (const float*)d_in[0];
    const float* w1k    = (const float*)d_in[1];
    const float* b1k    = (const float*)d_in[2];
    const float* w2k    = (const float*)d_in[3];
    const float* b2k    = (const float*)d_in[4];
    const float* w1b    = (const float*)d_in[5];
    const float* b1b    = (const float*)d_in[6];
    const float* w2b    = (const float*)d_in[7];
    const float* b2b    = (const float*)d_in[8];
    const float* conv_w = (const float*)d_in[9];
    const float* conv_b = (const float*)d_in[10];
    float* out = (float*)d_out;

    constexpr int L = 64 * 64;
    float* pk = (float*)d_ws;            // L*64 floats = 1 MiB
    float* pb = pk + (size_t)L * 64;     // L floats

    mlp_precompute<<<L / 4, 256, 0, stream>>>(w1k, b1k, w2k, b2k,
                                              w1b, b1b, w2b, b2b, pk, pb);

    // 2048 blocks: (128-col tile: 4) x (ph: 64) x (b: 8)
    dim3 grid(4, 64, 8);
    afpm_main<<<grid, 1024, 0, stream>>>(x, conv_w, conv_b, pk, pb, out);
}

// Round 10
// 302.888 us; speedup vs baseline: 1.8528x; 1.8528x over previous
//
#include <hip/hip_runtime.h>
#include <math.h>

// B=8, C=64, H=512, W=512, K=8, HID=64, nh=nw=64, L=4096
//
//  A) mlp_precompute: pk[L][64], pb[L] into d_ws (runs once, ~8 us).
//  B) afpm_main (R10): R8's geometry (tile 64c x 8r x 128cols, 256B/instr
//     per c-group, hole-free stores) but split into TWO sequential 64-col
//     phases so only 8 float4/thread are register-resident at once.
//     VGPR ~56 with __launch_bounds__(1024,8) -> 2 blocks/CU resident
//     (32 waves): block boundaries / phase drains of one block overlap the
//     other block's streaming. 3 barriers; f0 double-buffered by phase.
//     Thread (c:64, u:16): phase h handles cols [h*64+4u, +4) of 8 rows;
//     patch p = u>>1 (local 0..7 within phase), halves combined by
//     __shfl_xor(,1); conv by even-u threads; modulator broadcast in-wave.

static __device__ __forceinline__ float gelu_erf(float x) {
    return 0.5f * x * (1.0f + erff(x * 0.70710678118654752f));
}

__global__ __launch_bounds__(256) void mlp_precompute(
    const float* __restrict__ w1k, const float* __restrict__ b1k,
    const float* __restrict__ w2k, const float* __restrict__ b2k,
    const float* __restrict__ w1b, const float* __restrict__ b1b,
    const float* __restrict__ w2b, const float* __restrict__ b2b,
    float* __restrict__ pk_out,   // [L][64]
    float* __restrict__ pb_out)   // [L]
{
    constexpr int HID = 64;
    const int tid = threadIdx.x;
    const int pi  = tid >> 6;
    const int j   = tid & 63;
    const int l   = blockIdx.x * 4 + pi;

    const int py_i = l >> 6;
    const int px_i = l & 63;
    const float py = (float)(py_i * 8) + 4.0f - 256.0f;
    const float px = (float)(px_i * 8) + 4.0f - 256.0f;
    const float dd = sqrtf(py * py + px * px) * (1.0f / 362.03867196751236f);

    __shared__ float gk[4][HID];
    __shared__ float gb[4][HID];

    gk[pi][j] = gelu_erf(dd * w1k[j] + b1k[j]);
    gb[pi][j] = gelu_erf(dd * w1b[j] + b1b[j]);
    __syncthreads();

    float s = b2k[j];
#pragma unroll 8
    for (int h = 0; h < HID; ++h)
        s += gk[pi][h] * w2k[h * HID + j];
    pk_out[l * HID + j] = s;

    if (j == 0) {
        float t = b2b[0];
        for (int h = 0; h < HID; ++h)
            t += gb[pi][h] * w2b[h];
        pb_out[l] = t;
    }
}

__global__ __launch_bounds__(1024, 8) void afpm_main(
    const float* __restrict__ x,
    const float* __restrict__ conv_w, const float* __restrict__ conv_b,
    const float* __restrict__ pk_g,   // [L][64]
    const float* __restrict__ pb_g,   // [L]
    float* __restrict__ out)
{
    constexpr int W = 512;

    const int tid  = threadIdx.x;
    const int u    = tid & 15;         // 0..15: 4-col slice within phase
    const int c    = tid >> 4;         // 0..63: channel
    const int tile = blockIdx.x;       // 0..3 : 128-col tile
    const int ph   = blockIdx.y;       // 0..63
    const int b    = blockIdx.z;       // 0..7

    __shared__ float pkL[16][68];      // 16 patches x 64 elems (pad 68)
    __shared__ float f0[2][8][68];     // per-phase feats [phase][patch][cc]
    __shared__ float pbL[16];

    const int lbase = ph * 64 + tile * 16;

    // ---- stage pk/pb (issued first), then phase-0 pixel loads ----
    const float pkv = pk_g[(size_t)lbase * 64 + tid];
    const float pbv = (tid < 16) ? pb_g[lbase + tid] : 0.0f;

    const size_t base = (((size_t)b * 64 + c) * 512 + (size_t)ph * 8) * (size_t)W
                        + (size_t)(tile * 128);
    const float* xp0 = x + base + 4 * u;        // phase 0: cols [4u..4u+3]
    float4 v[8];
#pragma unroll
    for (int r = 0; r < 8; ++r)
        v[r] = *(const float4*)(xp0 + r * W);

    pkL[tid >> 6][tid & 63] = pkv;
    if (tid < 16) pbL[tid] = pbv;
    __syncthreads();                   // barrier A: pkL/pbL ready

    const int p  = u >> 1;             // local patch within phase (0..7)
    const int co = (u & 1) * 4;        // col offset within patch
    const int lane  = tid & 63;
    const int mlsrc = (lane & 48) | (u & 14);   // even-u lane of same (c,p)

    // ================= phase 0 =================
    {
        float s = 0.0f;
#pragma unroll
        for (int r = 0; r < 8; ++r) {
            const float4 a = v[r];
            const int k0 = r * 8 + co;
            s += a.x * pkL[p][k0 + 0] + a.y * pkL[p][k0 + 1]
               + a.z * pkL[p][k0 + 2] + a.w * pkL[p][k0 + 3];
        }
        s += __shfl_xor(s, 1);
        if ((u & 1) == 0) f0[0][p][c] = s + pbL[p];
        __syncthreads();               // barrier B: f0[0] ready

        float m_self = 0.0f;
        if ((u & 1) == 0) {
            float t = 0.0f;
            const float4* cw = (const float4*)(conv_w + (size_t)c * 64);
#pragma unroll
            for (int i = 0; i < 16; ++i) {
                const float4 w = cw[i];
                const float4 f = *(const float4*)&f0[0][p][i * 4];
                t += w.x * f.x + w.y * f.y + w.z * f.z + w.w * f.w;
            }
            m_self = t + conv_b[c];
        }
        const float m = __shfl(m_self, mlsrc);

        float* op = out + base + 4 * u;
#pragma unroll
        for (int r = 0; r < 8; ++r) {
            float4 a = v[r];
            a.x *= m; a.y *= m; a.z *= m; a.w *= m;
            *(float4*)(op + r * W) = a;
        }
    }

    // ================= phase 1 (cols +64, patches 8..15) =================
    {
        const float* xp1 = x + base + 64 + 4 * u;
#pragma unroll
        for (int r = 0; r < 8; ++r)
            v[r] = *(const float4*)(xp1 + r * W);

        float s = 0.0f;
#pragma unroll
        for (int r = 0; r < 8; ++r) {
            const float4 a = v[r];
            const int k0 = r * 8 + co;
            s += a.x * pkL[8 + p][k0 + 0] + a.y * pkL[8 + p][k0 + 1]
               + a.z * pkL[8 + p][k0 + 2] + a.w * pkL[8 + p][k0 + 3];
        }
        s += __shfl_xor(s, 1);
        if ((u & 1) == 0) f0[1][p][c] = s + pbL[8 + p];
        __syncthreads();               // barrier C: f0[1] ready

        float m_self = 0.0f;
        if ((u & 1) == 0) {
            float t = 0.0f;
            const float4* cw = (const float4*)(conv_w + (size_t)c * 64);
#pragma unroll
            for (int i = 0; i < 16; ++i) {
                const float4 w = cw[i];
                const float4 f = *(const float4*)&f0[1][p][i * 4];
                t += w.x * f.x + w.y * f.y + w.z * f.z + w.w * f.w;
            }
            m_self = t + conv_b[c];
        }
        const float m = __shfl(m_self, mlsrc);

        float* op = out + base + 64 + 4 * u;
#pragma unroll
        for (int r = 0; r < 8; ++r) {
            float4 a = v[r];
            a.x *= m; a.y *= m; a.z *= m; a.w *= m;
            *(float4*)(op + r * W) = a;
        }
    }
}

extern "C" void kernel_launch(void* const* d_in, const int* in_sizes, int n_in,
                              void* d_out, int out_size, void* d_ws, size_t ws_size,
                              hipStream_t stream) {
    const float* x      = (const float*)d_in[0];
    const float* w1k    = (const float*)d_in[1];
    const float* b1k    = (const float*)d_in[2];
    const float* w2k    = (const float*)d_in[3];
    const float* b2k    = (const float*)d_in[4];
    const float* w1b    = (const float*)d_in[5];
    const float* b1b    = (const float*)d_in[6];
    const float* w2b    = (const float*)d_in[7];
    const float* b2b    = (const float*)d_in[8];
    const float* conv_w = (const float*)d_in[9];
    const float* conv_b = (const float*)d_in[10];
    float* out = (float*)d_out;

    constexpr int L = 64 * 64;
    float* pk = (float*)d_ws;            // L*64 floats = 1 MiB
    float* pb = pk + (size_t)L * 64;     // L floats

    mlp_precompute<<<L / 4, 256, 0, stream>>>(w1k, b1k, w2k, b2k,
                                              w1b, b1b, w2b, b2b, pk, pb);

    // 2048 blocks: (128-col tile: 4) x (ph: 64) x (b: 8)
    dim3 grid(4, 64, 8);
    afpm_main<<<grid, 1024, 0, stream>>>(x, conv_w, conv_b, pk, pb, out);
}

// Round 11
// 229.382 us; speedup vs baseline: 2.4466x; 1.3205x over previous
//
#include <hip/hip_runtime.h>
#include <math.h>

// B=8, C=64, H=512, W=512, K=8, HID=64, nh=nw=64, L=4096
//
//  A) mlp_precompute: pk[L][64], pb[L] into d_ws (runs once, ~8 us).
//  B) afpm_main (R11) = R8 (best, 226.4 us) + NON-TEMPORAL stores.
//     1024 threads = (c:64 x u:16); tile = 64c x 8r x 128 cols (16 patches).
//     16 float4/thread register-resident; 2 barriers; pk/pb in LDS;
//     per-thread conv; modulators via in-wave __shfl.
//     Stores: __builtin_nontemporal_store (global_store_dwordx4 nt) --
//     bypass L2/L3 allocation to test the write-sector-inflation hypothesis
//     (R6/R10 showed WRITE_SIZE = 1.58x ideal for 128-256B write islands).

typedef float vf4 __attribute__((ext_vector_type(4)));

static __device__ __forceinline__ float gelu_erf(float x) {
    return 0.5f * x * (1.0f + erff(x * 0.70710678118654752f));
}

__global__ __launch_bounds__(256) void mlp_precompute(
    const float* __restrict__ w1k, const float* __restrict__ b1k,
    const float* __restrict__ w2k, const float* __restrict__ b2k,
    const float* __restrict__ w1b, const float* __restrict__ b1b,
    const float* __restrict__ w2b, const float* __restrict__ b2b,
    float* __restrict__ pk_out,   // [L][64]
    float* __restrict__ pb_out)   // [L]
{
    constexpr int HID = 64;
    const int tid = threadIdx.x;
    const int pi  = tid >> 6;
    const int j   = tid & 63;
    const int l   = blockIdx.x * 4 + pi;

    const int py_i = l >> 6;
    const int px_i = l & 63;
    const float py = (float)(py_i * 8) + 4.0f - 256.0f;
    const float px = (float)(px_i * 8) + 4.0f - 256.0f;
    const float dd = sqrtf(py * py + px * px) * (1.0f / 362.03867196751236f);

    __shared__ float gk[4][HID];
    __shared__ float gb[4][HID];

    gk[pi][j] = gelu_erf(dd * w1k[j] + b1k[j]);
    gb[pi][j] = gelu_erf(dd * w1b[j] + b1b[j]);
    __syncthreads();

    float s = b2k[j];
#pragma unroll 8
    for (int h = 0; h < HID; ++h)
        s += gk[pi][h] * w2k[h * HID + j];
    pk_out[l * HID + j] = s;

    if (j == 0) {
        float t = b2b[0];
        for (int h = 0; h < HID; ++h)
            t += gb[pi][h] * w2b[h];
        pb_out[l] = t;
    }
}

__global__ __launch_bounds__(1024, 4) void afpm_main(
    const float* __restrict__ x,
    const float* __restrict__ conv_w, const float* __restrict__ conv_b,
    const float* __restrict__ pk_g,   // [L][64]
    const float* __restrict__ pb_g,   // [L]
    float* __restrict__ out)
{
    constexpr int W = 512;

    const int tid  = threadIdx.x;
    const int u    = tid & 15;         // 0..15: 4-col slice within each half
    const int c    = tid >> 4;         // 0..63 channel
    const int tile = blockIdx.x;       // 0..3 : 128-col tile
    const int ph   = blockIdx.y;       // 0..63
    const int b    = blockIdx.z;       // 0..7

    __shared__ float pkL[16][68];      // 16 patches x 64 kernel elems (pad 68)
    __shared__ float f0T[16][68];      // [patch][cc], pad 68
    __shared__ float pbL[16];

    const int lbase = ph * 64 + tile * 16;   // first global patch of tile

    // ---- pixel loads: 16 float4; wave covers 4 planes x 512B per instr-pair
    const size_t base = (((size_t)b * 64 + c) * 512 + (size_t)ph * 8) * (size_t)W
                        + (size_t)(tile * 128);
    const float* xp0 = x + base + 4 * u;        // half0: cols [4u..4u+3]
    const float* xp1 = x + base + 64 + 4 * u;   // half1: +64
    float4 v0[8], v1[8];
#pragma unroll
    for (int r = 0; r < 8; ++r) {
        v0[r] = *(const float4*)(xp0 + r * W);
        v1[r] = *(const float4*)(xp1 + r * W);
    }

    // ---- stage pk (1024 floats = 1/thread) and pb ----
    pkL[tid >> 6][tid & 63] = pk_g[(size_t)lbase * 64 + tid];
    if (tid < 16) pbL[tid] = pb_g[lbase + tid];
    __syncthreads();                       // barrier 1

    // ---- per-thread partial dots for the two patches ----
    const int p0 = u >> 1;                 // patch in half0 (0..7)
    const int p1 = 8 + (u >> 1);           // patch in half1 (8..15)
    const int co = (u & 1) * 4;            // col offset within patch
    float s0 = 0.0f, s1 = 0.0f;
#pragma unroll
    for (int r = 0; r < 8; ++r) {
        const int k0 = r * 8 + co;
        const float4 a = v0[r];
        s0 += a.x * pkL[p0][k0 + 0] + a.y * pkL[p0][k0 + 1]
            + a.z * pkL[p0][k0 + 2] + a.w * pkL[p0][k0 + 3];
        const float4 d = v1[r];
        s1 += d.x * pkL[p1][k0 + 0] + d.y * pkL[p1][k0 + 1]
            + d.z * pkL[p1][k0 + 2] + d.w * pkL[p1][k0 + 3];
    }
    s0 += __shfl_xor(s0, 1);               // combine 4-col halves of patch
    s1 += __shfl_xor(s1, 1);
    if ((u & 1) == 0) f0T[p0][c] = s0 + pbL[p0];
    else              f0T[p1][c] = s1 + pbL[p1];
    __syncthreads();                       // barrier 2

    // ---- conv: thread (c,u) computes modulator for (o=c, patch=u) ----
    float t = 0.0f;
    const float4* cw = (const float4*)(conv_w + (size_t)c * 64);
#pragma unroll
    for (int i = 0; i < 16; ++i) {
        const float4 w = cw[i];
        const float4 f = *(const float4*)&f0T[u][i * 4];
        t += w.x * f.x + w.y * f.y + w.z * f.z + w.w * f.w;
    }
    const float m_self = t + conv_b[c];

    // fetch this thread's two modulators from the in-wave 16-lane c-group
    const int lane  = tid & 63;
    const int laneC = lane & 48;           // first lane of this c-group
    const float m0 = __shfl(m_self, laneC + p0);
    const float m1 = __shfl(m_self, laneC + p1);

    // ---- modulate + NON-TEMPORAL store (same span pattern as loads) ----
    float* op0 = out + base + 4 * u;
    float* op1 = out + base + 64 + 4 * u;
#pragma unroll
    for (int r = 0; r < 8; ++r) {
        vf4 a;
        a.x = v0[r].x * m0; a.y = v0[r].y * m0;
        a.z = v0[r].z * m0; a.w = v0[r].w * m0;
        __builtin_nontemporal_store(a, (vf4*)(op0 + r * W));
        vf4 d;
        d.x = v1[r].x * m1; d.y = v1[r].y * m1;
        d.z = v1[r].z * m1; d.w = v1[r].w * m1;
        __builtin_nontemporal_store(d, (vf4*)(op1 + r * W));
    }
}

extern "C" void kernel_launch(void* const* d_in, const int* in_sizes, int n_in,
                              void* d_out, int out_size, void* d_ws, size_t ws_size,
                              hipStream_t stream) {
    const float* x      = (const float*)d_in[0];
    const float* w1k    = (const float*)d_in[1];
    const float* b1k    = (const float*)d_in[2];
    const float* w2k    = (const float*)d_in[3];
    const float* b2k    = (const float*)d_in[4];
    const float* w1b    = (const float*)d_in[5];
    const float* b1b    = (const float*)d_in[6];
    const float* w2b    = (const float*)d_in[7];
    const float* b2b    = (const float*)d_in[8];
    const float* conv_w = (const float*)d_in[9];
    const float* conv_b = (const float*)d_in[10];
    float* out = (float*)d_out;

    constexpr int L = 64 * 64;
    float* pk = (float*)d_ws;            // L*64 floats = 1 MiB
    float* pb = pk + (size_t)L * 64;     // L floats

    mlp_precompute<<<L / 4, 256, 0, stream>>>(w1k, b1k, w2k, b2k,
                                              w1b, b1b, w2b, b2b, pk, pb);

    // 2048 blocks: (128-col tile: 4) x (ph: 64) x (b: 8)
    dim3 grid(4, 64, 8);
    afpm_main<<<grid, 1024, 0, stream>>>(x, conv_w, conv_b, pk, pb, out);
}